// Round 7
// baseline (496.584 us; speedup 1.0000x reference)
//
#include <hip/hip_runtime.h>

// ---------------------------------------------------------------------------
// GCN 2-layer forward, round 19.
// Round-18 post-mortem: FAILED (container died twice, no counters). Cause is
// hipLaunchCooperativeKernel x graph-capture (unsupported) or grid.sync
// deadlock. Cooperative launch abandoned; fusion idea retained via MANUAL
// device-scope barrier under a plain launch (capture-legal).
// Round-19 delta (from r17 known-good 198.0us):
//   * k_count also builds deg[] (global atomicAdd; reads col anyway).
//     dinv = rsqrtf(deg) computed at use; dinv array deleted. gemm1 now
//     depends only on k_count.
//   * k_scgm: scatter (blocks < numTiles) || gemm1 (next 1024 blocks) in one
//     launch - disjoint data, no sync needed.
//   * k_tail: agg1 -> BAR -> gemm2 -> BAR -> agg2 in one kernel. Manual
//     barrier: release atomicAdd + acquire spin (bar memset each launch).
//     Residency: launch_bounds(256,4) caps VGPR 128 -> 4 blocks/CU capacity;
//     grid 768 = 3/CU; LDS 16.9KB x 4 = 67.6 <= 160KB. No deadlock if cap
//     holds (compiler-enforced).
// Pipeline: memset, count(+deg), scan, scgm, bfill, tail. 5 kernels+1 memset
// (was 8 kernels).
// ---------------------------------------------------------------------------

#define BSH 8        // bucket shift: 256 nodes per bucket
#define BSZ 256
#define PTILE 4096   // messages per partition tile
#define CAP 6144     // fixed bucket capacity (slots)
#define PADALLOW 3856
#define CROW (CAP + PADALLOW)  // per-bucket csrc region
#define GEMMB 1024   // gemm1 blocks inside k_scgm
#define TGRID 768    // tail fused kernel grid: 3 blocks/CU (residency-safe)

typedef __attribute__((ext_vector_type(8))) short bf16x8;
typedef __attribute__((ext_vector_type(4))) float f32x4;

__device__ __forceinline__ unsigned bf16_rne(float f) {
    unsigned b = __float_as_uint(f);
    return (b + 0x7fffu + ((b >> 16) & 1u)) >> 16;
}
__device__ __forceinline__ float bf16_lo(unsigned u) { return __uint_as_float(u << 16); }
__device__ __forceinline__ float bf16_hi(unsigned u) { return __uint_as_float(u & 0xffff0000u); }

// Manual grid barrier (device scope). Requires all blocks resident.
__device__ __forceinline__ void gbar(int* bar, int idx, int nblk) {
    __syncthreads();
    if (threadIdx.x == 0) {
        __threadfence();
        __hip_atomic_fetch_add(&bar[idx], 1, __ATOMIC_ACQ_REL, __HIP_MEMORY_SCOPE_AGENT);
        while (__hip_atomic_load(&bar[idx], __ATOMIC_ACQUIRE, __HIP_MEMORY_SCOPE_AGENT) < nblk)
            __builtin_amdgcn_s_sleep(1);
    }
    __syncthreads();
}

// Per-tile bucket histogram into tcnt[tile][b]; also global deg[] histogram.
__global__ __launch_bounds__(512) void k_count(const int* __restrict__ coli,
                                               int E, int N, int NB, int numTiles,
                                               int* __restrict__ tcnt,
                                               int* __restrict__ deg) {
    __shared__ int hist[512];
    int t = threadIdx.x;
    int T = E + N;
    int tile = blockIdx.x;
    int tstart = tile * PTILE;
    int m = min(PTILE, T - tstart);
    for (int b = t; b < NB; b += 512) hist[b] = 0;
    __syncthreads();
    for (int i = t; i < m; i += 512) {
        int g = tstart + i;
        int c = (g < E) ? coli[g] : (g - E);
        atomicAdd(&hist[c >> BSH], 1);
        atomicAdd(&deg[c], 1);
    }
    __syncthreads();
    for (int b = t; b < NB; b += 512) tcnt[tile * NB + b] = hist[b];
}

// Block-per-bucket exclusive scan over tiles (chunked, wave-shuffle).
__global__ __launch_bounds__(512) void k_scan(int* __restrict__ tcnt,
                                              int* __restrict__ btot,
                                              int NB, int numTiles) {
    __shared__ int wsum[8];
    int b = blockIdx.x;
    int t = threadIdx.x;
    int lane = t & 63, wid = t >> 6;
    int base = 0;
    for (int c0 = 0; c0 < numTiles; c0 += 512) {
        int tt = c0 + t;
        int v = (tt < numTiles) ? tcnt[tt * NB + b] : 0;
        int inc = v;
        #pragma unroll
        for (int d = 1; d < 64; d <<= 1) {
            int o = __shfl_up(inc, d);
            if (lane >= d) inc += o;
        }
        if (lane == 63) wsum[wid] = inc;
        __syncthreads();
        int woff = 0, ctot = 0;
        #pragma unroll
        for (int i = 0; i < 8; i++) {
            int s = wsum[i];
            if (i < wid) woff += s;
            ctot += s;
        }
        if (tt < numTiles) tcnt[tt * NB + b] = b * CAP + base + woff + inc - v;
        base += ctot;
        __syncthreads();
    }
    if (t == 0) btot[b] = base;
}

// H[row] = rsqrt(deg[row]) * (X[row] @ W), bf16 out; zero sentinel row at N.
// NT = block threads (NT/64 waves). blkLocal/nBlkLocal define slab striding.
template <bool BF16IN, int NT>
__device__ __forceinline__ void gemm_body(const void* __restrict__ Xv,
                                          const float* __restrict__ W,
                                          const int* __restrict__ deg,
                                          unsigned* __restrict__ Hout,
                                          int N, int nSlabs, int blkLocal,
                                          int nBlkLocal, float* SMEM) {
    int t = threadIdx.x;
    int lane = t & 63, w = t >> 6;
    int nn = lane & 15, kq = lane >> 4;
    constexpr int NW = NT / 64;

    for (int i = t; i < 1024; i += NT) ((float4*)SMEM)[i] = ((const float4*)W)[i];
    __syncthreads();
    bf16x8 Bf[2][4];
    #pragma unroll
    for (int kt = 0; kt < 2; kt++) {
        #pragma unroll
        for (int ct = 0; ct < 4; ct++) {
            union { bf16x8 v; unsigned short s[8]; } u;
            #pragma unroll
            for (int j = 0; j < 8; j++) {
                int k = kt * 32 + kq * 8 + j;
                u.s[j] = (unsigned short)bf16_rne(SMEM[k * 64 + ct * 16 + nn]);
            }
            Bf[kt][ct] = u.v;
        }
    }
    __syncthreads();  // W region dead; SMEM becomes per-wave transpose scratch

    float* outT = SMEM + w * 1056;  // 16 rows x 66 floats

    for (int slab = blkLocal * NW + w; slab < nSlabs; slab += nBlkLocal * NW) {
        int row0 = slab * 16;
        int rowA = min(row0 + nn, N - 1);
        bf16x8 A0, A1;
        if (BF16IN) {
            const uint4* X = (const uint4*)Xv;  // row = 8 uint4
            union { uint4 u; bf16x8 v; } a0, a1;
            a0.u = X[(size_t)rowA * 8 + kq];
            a1.u = X[(size_t)rowA * 8 + 4 + kq];
            A0 = a0.v; A1 = a1.v;
        } else {
            const float4* X = (const float4*)Xv;  // row = 16 float4
            float4 f0 = X[(size_t)rowA * 16 + kq * 2];
            float4 f1 = X[(size_t)rowA * 16 + kq * 2 + 1];
            float4 f2 = X[(size_t)rowA * 16 + 8 + kq * 2];
            float4 f3 = X[(size_t)rowA * 16 + 8 + kq * 2 + 1];
            union { bf16x8 v; unsigned short s[8]; } a0, a1;
            a0.s[0] = (unsigned short)bf16_rne(f0.x); a0.s[1] = (unsigned short)bf16_rne(f0.y);
            a0.s[2] = (unsigned short)bf16_rne(f0.z); a0.s[3] = (unsigned short)bf16_rne(f0.w);
            a0.s[4] = (unsigned short)bf16_rne(f1.x); a0.s[5] = (unsigned short)bf16_rne(f1.y);
            a0.s[6] = (unsigned short)bf16_rne(f1.z); a0.s[7] = (unsigned short)bf16_rne(f1.w);
            a1.s[0] = (unsigned short)bf16_rne(f2.x); a1.s[1] = (unsigned short)bf16_rne(f2.y);
            a1.s[2] = (unsigned short)bf16_rne(f2.z); a1.s[3] = (unsigned short)bf16_rne(f2.w);
            a1.s[4] = (unsigned short)bf16_rne(f3.x); a1.s[5] = (unsigned short)bf16_rne(f3.y);
            a1.s[6] = (unsigned short)bf16_rne(f3.z); a1.s[7] = (unsigned short)bf16_rne(f3.w);
            A0 = a0.v; A1 = a1.v;
        }
        float dvm = rsqrtf((float)deg[rowA]);

        f32x4 acc[4];
        #pragma unroll
        for (int ct = 0; ct < 4; ct++) acc[ct] = (f32x4){0.f, 0.f, 0.f, 0.f};
        #pragma unroll
        for (int ct = 0; ct < 4; ct++) {
            acc[ct] = __builtin_amdgcn_mfma_f32_16x16x32_bf16(A0, Bf[0][ct], acc[ct], 0, 0, 0);
            acc[ct] = __builtin_amdgcn_mfma_f32_16x16x32_bf16(A1, Bf[1][ct], acc[ct], 0, 0, 0);
        }

        #pragma unroll
        for (int reg = 0; reg < 4; reg++) {
            int r = kq * 4 + reg;
            float dv = __shfl(dvm, r);
            #pragma unroll
            for (int ct = 0; ct < 4; ct++) {
                outT[r * 66 + ct * 16 + nn] = acc[ct][reg] * dv;
            }
        }
        int rr = lane >> 2;
        int c0 = (lane & 3) * 16;
        int orow = row0 + rr;
        if (orow < N) {
            unsigned pk[8];
            #pragma unroll
            for (int i = 0; i < 8; i++) {
                float lo = outT[rr * 66 + c0 + 2 * i];
                float hi = outT[rr * 66 + c0 + 2 * i + 1];
                pk[i] = bf16_rne(lo) | (bf16_rne(hi) << 16);
            }
            uint4* dst = (uint4*)Hout + (size_t)orow * 8 + (lane & 3) * 2;
            dst[0] = make_uint4(pk[0], pk[1], pk[2], pk[3]);
            dst[1] = make_uint4(pk[4], pk[5], pk[6], pk[7]);
        } else if (orow == N) {  // zero sentinel row
            uint4* dst = (uint4*)Hout + (size_t)N * 8 + (lane & 3) * 2;
            dst[0] = make_uint4(0, 0, 0, 0);
            dst[1] = make_uint4(0, 0, 0, 0);
        }
    }
}

// Fused: scatter (blocks < numTiles) || gemm1 (next GEMMB blocks).
__global__ __launch_bounds__(512, 2) void k_scgm(const int* __restrict__ rowi,
                                                 const int* __restrict__ coli,
                                                 int E, int N, int NB, int numTiles,
                                                 const int* __restrict__ tcnt,
                                                 unsigned* __restrict__ pairs,
                                                 const float* __restrict__ x,
                                                 const float* __restrict__ W1,
                                                 const int* __restrict__ deg,
                                                 unsigned* __restrict__ hbuf,
                                                 int nSlabs) {
    __shared__ int SH[8448];
    int bid = blockIdx.x;
    int t = threadIdx.x;
    if (bid >= numTiles) {
        gemm_body<false, 512>(x, W1, deg, hbuf, N, nSlabs, bid - numTiles, GEMMB,
                              (float*)SH);
        return;
    }
    // ---- scatter: LDS counting sort per tile, coalesced pairs writes ----
    int* hist = SH;                      // counts, then cursors
    int* lbase = SH + 512;
    int* gbase = SH + 1024;
    unsigned* sorted = (unsigned*)(SH + 1536);      // [4096]
    unsigned short* sbkt = (unsigned short*)(SH + 5632);  // [4096] ushort
    int* wsum = SH + 7680;               // [8]
    int T = E + N;
    int tstart = bid * PTILE;
    int m = min(PTILE, T - tstart);
    int lane = t & 63, wid = t >> 6;
    for (int b = t; b < NB; b += 512) {
        hist[b] = 0;
        gbase[b] = tcnt[bid * NB + b];
    }
    __syncthreads();
    int c_reg[8];
    #pragma unroll
    for (int k = 0; k < 8; k++) {
        int i = t + k * 512;
        int c = 0;
        if (i < m) {
            int g = tstart + i;
            c = (g < E) ? coli[g] : (g - E);
            atomicAdd(&hist[c >> BSH], 1);
        }
        c_reg[k] = c;
    }
    __syncthreads();
    {   // block exclusive scan of hist -> lbase
        int v = (t < NB) ? hist[t] : 0;
        int inc = v;
        #pragma unroll
        for (int d = 1; d < 64; d <<= 1) {
            int o = __shfl_up(inc, d);
            if (lane >= d) inc += o;
        }
        if (lane == 63) wsum[wid] = inc;
        __syncthreads();
        int woff = 0;
        for (int i = 0; i < wid; i++) woff += wsum[i];
        if (t < NB) lbase[t] = woff + inc - v;
        __syncthreads();
    }
    for (int b = t; b < NB; b += 512) hist[b] = 0;  // reuse as cursors
    __syncthreads();
    #pragma unroll
    for (int k = 0; k < 8; k++) {
        int i = t + k * 512;
        if (i < m) {
            int g = tstart + i;
            int c = c_reg[k];
            int r = (g < E) ? rowi[g] : c;  // self-loop tail has r == c
            int b = c >> BSH;
            int lr = atomicAdd(&hist[b], 1);
            int pos = lbase[b] + lr;
            sorted[pos] = (unsigned)r | ((unsigned)(c & (BSZ - 1)) << 24);
            sbkt[pos] = (unsigned short)b;
        }
    }
    __syncthreads();
    for (int j = t; j < m; j += 512) {
        int b = sbkt[j];
        pairs[gbase[b] + (j - lbase[b])] = sorted[j];
    }
}

// One block per bucket: per-node histogram, padded scan, build csrc in LDS,
// coalesced copy out. Emits offsets/cnt (no dinv: deg[] covers it).
__global__ __launch_bounds__(1024) void k_bfill(const unsigned* __restrict__ pairs,
                                                const int* __restrict__ btot,
                                                int N,
                                                int* __restrict__ offsets,
                                                int* __restrict__ cnt,
                                                int* __restrict__ csrc) {
    __shared__ int scnt[BSZ];
    __shared__ int scur[BSZ];
    __shared__ int wsum[4];
    __shared__ int scsrc[CROW];
    int b = blockIdx.x;
    int t = threadIdx.x;
    int ebeg = b * CAP;
    int m = btot[b];
    int pbase = b * CROW;
    int lane = t & 63, wid = t >> 6;
    if (t < BSZ) scnt[t] = 0;
    __syncthreads();
    for (int i = t; i < m; i += 1024) atomicAdd(&scnt[pairs[ebeg + i] >> 24], 1);
    __syncthreads();
    int cval = 0, pc = 0, inc = 0;
    if (t < BSZ) {
        cval = scnt[t];
        pc = (cval + 15) & ~15;
        inc = pc;
        #pragma unroll
        for (int d = 1; d < 64; d <<= 1) {
            int o = __shfl_up(inc, d);
            if (lane >= d) inc += o;
        }
        if (lane == 63) wsum[wid] = inc;
    }
    __syncthreads();
    if (t < BSZ) {
        int woff = 0;
        for (int i = 0; i < wid; i++) woff += wsum[i];
        int offl = woff + inc - pc;
        int v = (b << BSH) + t;
        if (v < N) {
            offsets[v] = pbase + offl;
            cnt[v] = (cval + 1) & ~1;
        }
        scur[t] = offl;
        for (int i = offl + cval; i < offl + pc; i++) scsrc[i] = N;  // sentinels
    }
    __syncthreads();
    for (int i = t; i < m; i += 1024) {
        unsigned pk = pairs[ebeg + i];
        int slot = atomicAdd(&scur[pk >> 24], 1);
        scsrc[slot] = (int)(pk & 0xFFFFFFu);
    }
    __syncthreads();
    int tot = wsum[0] + wsum[1] + wsum[2] + wsum[3];
    for (int j = t; j < tot; j += 1024) csrc[pbase + j] = scsrc[j];
}

#define ACC8(R) do {                                                        \
        uint4 dd = *(const uint4*)(hb + ((unsigned)(R) << 7));              \
        a0 += bf16_lo(dd.x); a1 += bf16_hi(dd.x);                           \
        a2 += bf16_lo(dd.y); a3 += bf16_hi(dd.y);                           \
        a4 += bf16_lo(dd.z); a5 += bf16_hi(dd.z);                           \
        a6 += bf16_lo(dd.w); a7 += bf16_hi(dd.w);                           \
    } while (0)

// out[v] = epi( rsqrt(deg[v]) * sum_{j in CSR[v]} H[src_j] + bias )
template <bool RELU_BF16OUT>
__device__ __forceinline__ void agg_body(const uint4* __restrict__ H,
                                         const int* __restrict__ offsets,
                                         const int* __restrict__ cnt,
                                         const int* __restrict__ csrc,
                                         const int* __restrict__ deg,
                                         const float* __restrict__ bias,
                                         void* __restrict__ outv, int N,
                                         int blk, int nblk) {
    int t = threadIdx.x;
    int fl = t & 7;
    const char* hb = (const char*)H + ((unsigned)fl << 4);
    const float4* b4 = (const float4*)bias;
    float4 bA = b4[fl * 2];
    float4 bB = b4[fl * 2 + 1];
    for (int v = blk * 32 + (t >> 3); v < N; v += nblk * 32) {
        int beg = offsets[v];
        int dg = cnt[v];  // true count rounded to x2
        const int2* cs2 = (const int2*)(csrc + beg);
        float a0 = 0.f, a1 = 0.f, a2 = 0.f, a3 = 0.f;
        float a4 = 0.f, a5 = 0.f, a6 = 0.f, a7 = 0.f;
        int2 ss = cs2[0];
        for (int j = 2; j < dg; j += 2) {
            int2 nx = cs2[j >> 1];
            ACC8(ss.x);
            ACC8(ss.y);
            ss = nx;
        }
        ACC8(ss.x);
        ACC8(ss.y);
        float dv = rsqrtf((float)deg[v]);
        float r0 = fmaf(dv, a0, bA.x);
        float r1 = fmaf(dv, a1, bA.y);
        float r2 = fmaf(dv, a2, bA.z);
        float r3 = fmaf(dv, a3, bA.w);
        float r4 = fmaf(dv, a4, bB.x);
        float r5 = fmaf(dv, a5, bB.y);
        float r6 = fmaf(dv, a6, bB.z);
        float r7 = fmaf(dv, a7, bB.w);
        if (RELU_BF16OUT) {
            r0 = fmaxf(r0, 0.f); r1 = fmaxf(r1, 0.f);
            r2 = fmaxf(r2, 0.f); r3 = fmaxf(r3, 0.f);
            r4 = fmaxf(r4, 0.f); r5 = fmaxf(r5, 0.f);
            r6 = fmaxf(r6, 0.f); r7 = fmaxf(r7, 0.f);
            uint4 pk;
            pk.x = bf16_rne(r0) | (bf16_rne(r1) << 16);
            pk.y = bf16_rne(r2) | (bf16_rne(r3) << 16);
            pk.z = bf16_rne(r4) | (bf16_rne(r5) << 16);
            pk.w = bf16_rne(r6) | (bf16_rne(r7) << 16);
            ((uint4*)outv)[(size_t)v * 8 + fl] = pk;
        } else {
            float4* o = (float4*)outv + (size_t)v * 16 + fl * 2;
            o[0] = make_float4(r0, r1, r2, r3);
            o[1] = make_float4(r4, r5, r6, r7);
        }
    }
}

// Fused tail: agg1 -> barrier -> gemm2 -> barrier -> agg2.
__global__ __launch_bounds__(256, 4) void k_tail(const int* __restrict__ offsets,
                                                 const int* __restrict__ cnt,
                                                 const int* __restrict__ csrc,
                                                 const int* __restrict__ deg,
                                                 const float* __restrict__ b1,
                                                 const float* __restrict__ W2,
                                                 const float* __restrict__ b2,
                                                 unsigned* hbuf, unsigned* abuf,
                                                 float* __restrict__ out,
                                                 int N, int nSlabs, int* bar) {
    __shared__ float SMEM[4224];
    int bid = blockIdx.x;
    agg_body<true>((const uint4*)hbuf, offsets, cnt, csrc, deg, b1, abuf, N,
                   bid, TGRID);
    gbar(bar, 0, TGRID);
    gemm_body<true, 256>(abuf, W2, deg, hbuf, N, nSlabs, bid, TGRID, SMEM);
    gbar(bar, 1, TGRID);
    agg_body<false>((const uint4*)hbuf, offsets, cnt, csrc, deg, b2, out, N,
                    bid, TGRID);
}

extern "C" void kernel_launch(void* const* d_in, const int* in_sizes, int n_in,
                              void* d_out, int out_size, void* d_ws, size_t ws_size,
                              hipStream_t stream) {
    const float* x  = (const float*)d_in[0];
    const int*   ei = (const int*)d_in[1];  // harness delivers int32
    const float* W1 = (const float*)d_in[2];
    const float* b1 = (const float*)d_in[3];
    const float* W2 = (const float*)d_in[4];
    const float* b2 = (const float*)d_in[5];
    float* out      = (float*)d_out;

    const int N = in_sizes[0] / 64;
    const int E = in_sizes[1] / 2;
    const int* row = ei;
    const int* col = ei + E;
    const int T = E + N;
    const int NB = (N + BSZ - 1) >> BSH;           // buckets
    const int numTiles = (T + PTILE - 1) / PTILE;  // tiles

    char* p = (char*)d_ws;
    auto alloc = [&](size_t bytes) { void* r = (void*)p; p += (bytes + 255) & ~(size_t)255; return r; };
    int*      barDeg  = (int*)alloc((size_t)(16 + N) * 4);  // bar[16] + deg[N]
    int*      bar     = barDeg;
    int*      deg     = barDeg + 16;
    int*      tcnt    = (int*)alloc((size_t)NB * numTiles * 4);
    int*      btot    = (int*)alloc((size_t)(NB + 1) * 4);
    int*      offsets = (int*)alloc((size_t)N * 4);
    int*      cnt     = (int*)alloc((size_t)N * 4);
    unsigned* pairs   = (unsigned*)alloc((size_t)NB * CAP * 4);
    int*      csrc    = (int*)alloc(((size_t)NB * CROW + 64) * 4);
    unsigned* hbuf    = (unsigned*)alloc((size_t)(N + 16) * 32 * 4);  // bf16, +zero row
    unsigned* abuf    = (unsigned*)alloc((size_t)(N + 16) * 32 * 4);  // bf16, +zero row

    const int nSlabs = (N + 16) / 16;  // covers zero sentinel row N

    hipMemsetAsync(barDeg, 0, (size_t)(16 + N) * 4, stream);
    k_count<<<numTiles, 512, 0, stream>>>(col, E, N, NB, numTiles, tcnt, deg);
    k_scan<<<NB, 512, 0, stream>>>(tcnt, btot, NB, numTiles);
    k_scgm<<<numTiles + GEMMB, 512, 0, stream>>>(row, col, E, N, NB, numTiles,
                                                 tcnt, pairs, x, W1, deg, hbuf,
                                                 nSlabs);
    k_bfill<<<NB, 1024, 0, stream>>>(pairs, btot, N, offsets, cnt, csrc);
    k_tail<<<TGRID, 256, 0, stream>>>(offsets, cnt, csrc, deg, b1, W2, b2,
                                      hbuf, abuf, out, N, nSlabs, bar);
}

// Round 8
// 218.467 us; speedup vs baseline: 2.2730x; 2.2730x over previous
//
#include <hip/hip_runtime.h>

// ---------------------------------------------------------------------------
// GCN 2-layer forward, round 20.
// Round-19 post-mortem: FAILED 496.6us. k_tail=323us @ occ 35%, HBM 9% ->
// fusing latency-bound agg into a residency-capped grid (12 waves/CU vs
// 21-32 standalone) starved TLP ~3x. Also deg[] global atomics in k_count
// re-introduced the random-4B-write anti-pattern (front half ~173us).
// Both r19 mechanisms reverted; base = r17 known-good (198.0us).
// Round-20 delta (ONE mechanism): degree-sorted agg order.
//   * k_bfill: bucket-local LDS counting sort of its 256 nodes by degree
//     (keys already in scnt) -> perm[b*256+rank] = v. Dense permutation.
//   * k_agg: v = perm[idx]. The 8 nodes of a wave now have ~equal degree,
//     removing the exec-masked waste (wave runs max-of-8 degrees; Poisson
//     mean 17 -> E[max of 8] ~26 vs mean 18 = ~30% waste).
//   Per-node sum order unchanged -> absmax must stay 0.001953125 exactly.
// Pipeline: count, scan, scatter, bfill, gemm1, agg1, gemm2, agg2 (as r17).
// ---------------------------------------------------------------------------

#define NPB 32       // nodes per block (agg): 256 thr / 8-lane groups
#define BSH 8        // bucket shift: 256 nodes per bucket
#define BSZ 256
#define PTILE 4096   // messages per partition tile
#define CAP 6144     // fixed bucket capacity (slots)
#define PADALLOW 3856
#define CROW (CAP + PADALLOW)  // per-bucket csrc region

typedef __attribute__((ext_vector_type(8))) short bf16x8;
typedef __attribute__((ext_vector_type(4))) float f32x4;

__device__ __forceinline__ unsigned bf16_rne(float f) {
    unsigned b = __float_as_uint(f);
    return (b + 0x7fffu + ((b >> 16) & 1u)) >> 16;
}
__device__ __forceinline__ float bf16_lo(unsigned u) { return __uint_as_float(u << 16); }
__device__ __forceinline__ float bf16_hi(unsigned u) { return __uint_as_float(u & 0xffff0000u); }

// Per-tile bucket histogram. tcnt layout: [tile][bucket].
__global__ __launch_bounds__(512) void k_count(const int* __restrict__ coli,
                                               int E, int N, int NB, int numTiles,
                                               int* __restrict__ tcnt) {
    __shared__ int hist[512];
    int t = threadIdx.x;
    int T = E + N;
    int tile = blockIdx.x;
    int tstart = tile * PTILE;
    int m = min(PTILE, T - tstart);
    for (int b = t; b < NB; b += 512) hist[b] = 0;
    __syncthreads();
    for (int i = t; i < m; i += 512) {
        int g = tstart + i;
        int c = (g < E) ? coli[g] : (g - E);
        atomicAdd(&hist[c >> BSH], 1);
    }
    __syncthreads();
    for (int b = t; b < NB; b += 512) tcnt[(size_t)tile * NB + b] = hist[b];
}

// Block-per-bucket exclusive scan over tiles (chunked, wave-shuffle).
__global__ __launch_bounds__(512) void k_scan(int* __restrict__ tcnt,
                                              int* __restrict__ btot,
                                              int NB, int numTiles) {
    __shared__ int wsum[8];
    int b = blockIdx.x;
    int t = threadIdx.x;
    int lane = t & 63, wid = t >> 6;
    int base = 0;
    for (int c0 = 0; c0 < numTiles; c0 += 512) {
        int tt = c0 + t;
        int v = (tt < numTiles) ? tcnt[(size_t)tt * NB + b] : 0;
        int inc = v;
        #pragma unroll
        for (int d = 1; d < 64; d <<= 1) {
            int o = __shfl_up(inc, d);
            if (lane >= d) inc += o;
        }
        if (lane == 63) wsum[wid] = inc;
        __syncthreads();
        int woff = 0, ctot = 0;
        #pragma unroll
        for (int i = 0; i < 8; i++) {
            int s = wsum[i];
            if (i < wid) woff += s;
            ctot += s;
        }
        if (tt < numTiles) tcnt[(size_t)tt * NB + b] = b * CAP + base + woff + inc - v;
        base += ctot;
        __syncthreads();
    }
    if (t == 0) btot[b] = base;
}

// Scatter: LDS counting sort per tile, coalesced pairs writes.
__global__ __launch_bounds__(512) void k_scatter(const int* __restrict__ rowi,
                                                 const int* __restrict__ coli,
                                                 int E, int N, int NB, int numTiles,
                                                 const int* __restrict__ tcnt,
                                                 unsigned* __restrict__ pairs) {
    __shared__ int hist[512];
    __shared__ int lbase[512];
    __shared__ int gbase[512];
    __shared__ unsigned sorted[PTILE];
    __shared__ unsigned short sbkt[PTILE];
    __shared__ int wsum[8];
    int t = threadIdx.x;
    int T = E + N;
    int tile = blockIdx.x;
    int tstart = tile * PTILE;
    int m = min(PTILE, T - tstart);
    int lane = t & 63, wid = t >> 6;
    for (int b = t; b < NB; b += 512) {
        hist[b] = 0;
        gbase[b] = tcnt[(size_t)tile * NB + b];
    }
    __syncthreads();
    int c_reg[8];
    #pragma unroll
    for (int k = 0; k < 8; k++) {
        int i = t + k * 512;
        int c = 0;
        if (i < m) {
            int g = tstart + i;
            c = (g < E) ? coli[g] : (g - E);
            atomicAdd(&hist[c >> BSH], 1);
        }
        c_reg[k] = c;
    }
    __syncthreads();
    {   // block exclusive scan of hist -> lbase
        int v = (t < NB) ? hist[t] : 0;
        int inc = v;
        #pragma unroll
        for (int d = 1; d < 64; d <<= 1) {
            int o = __shfl_up(inc, d);
            if (lane >= d) inc += o;
        }
        if (lane == 63) wsum[wid] = inc;
        __syncthreads();
        int woff = 0;
        for (int i = 0; i < wid; i++) woff += wsum[i];
        if (t < NB) lbase[t] = woff + inc - v;
        __syncthreads();
    }
    for (int b = t; b < NB; b += 512) hist[b] = 0;  // reuse as cursors
    __syncthreads();
    #pragma unroll
    for (int k = 0; k < 8; k++) {
        int i = t + k * 512;
        if (i < m) {
            int g = tstart + i;
            int c = c_reg[k];
            int r = (g < E) ? rowi[g] : c;  // self-loop tail has r == c
            int b = c >> BSH;
            int lr = atomicAdd(&hist[b], 1);
            int pos = lbase[b] + lr;
            sorted[pos] = (unsigned)r | ((unsigned)(c & (BSZ - 1)) << 24);
            sbkt[pos] = (unsigned short)b;
        }
    }
    __syncthreads();
    for (int j = t; j < m; j += 512) {
        int b = sbkt[j];
        pairs[gbase[b] + (j - lbase[b])] = sorted[j];
    }
}

// One block per bucket: per-node histogram, padded scan, build csrc in LDS,
// coalesced copy out. NEW: bucket-local counting sort by degree -> perm.
__global__ __launch_bounds__(1024) void k_bfill(const unsigned* __restrict__ pairs,
                                                const int* __restrict__ btot,
                                                int N,
                                                int* __restrict__ offsets,
                                                int* __restrict__ cnt,
                                                float* __restrict__ dinv,
                                                int* __restrict__ csrc,
                                                int* __restrict__ perm) {
    __shared__ int scnt[BSZ];
    __shared__ int scur[BSZ];
    __shared__ int wsum[4];
    __shared__ int sbin[256];   // degree-sort bins
    __shared__ int wsum2[4];
    __shared__ int scsrc[CROW];
    int b = blockIdx.x;
    int t = threadIdx.x;
    int ebeg = b * CAP;
    int m = btot[b];
    int pbase = b * CROW;
    int lane = t & 63, wid = t >> 6;
    if (t < BSZ) { scnt[t] = 0; sbin[t] = 0; }
    __syncthreads();
    for (int i = t; i < m; i += 1024) atomicAdd(&scnt[pairs[ebeg + i] >> 24], 1);
    __syncthreads();
    int cval = 0, pc = 0, inc = 0;
    int v = (b << BSH) + t;
    bool v_ok = (t < BSZ) && (v < N);
    int key = 0;
    if (t < BSZ) {
        cval = scnt[t];
        pc = (cval + 15) & ~15;
        inc = pc;
        #pragma unroll
        for (int d = 1; d < 64; d <<= 1) {
            int o = __shfl_up(inc, d);
            if (lane >= d) inc += o;
        }
        if (lane == 63) wsum[wid] = inc;
        key = min(cval, 255);
    }
    if (v_ok) atomicAdd(&sbin[key], 1);
    __syncthreads();
    // exclusive scan of sbin -> cursor bases (t < 256, 4 waves)
    int bv = 0, binc = 0;
    if (t < 256) {
        bv = sbin[t];
        binc = bv;
        #pragma unroll
        for (int d = 1; d < 64; d <<= 1) {
            int o = __shfl_up(binc, d);
            if (lane >= d) binc += o;
        }
        if (lane == 63) wsum2[wid] = binc;
    }
    __syncthreads();
    if (t < 256) {
        int woff2 = 0;
        for (int i = 0; i < wid; i++) woff2 += wsum2[i];
        sbin[t] = woff2 + binc - bv;  // exclusive base, reused as cursor
    }
    if (t < BSZ) {
        int woff = 0;
        for (int i = 0; i < wid; i++) woff += wsum[i];
        int offl = woff + inc - pc;
        if (v_ok) {
            offsets[v] = pbase + offl;
            cnt[v] = (cval + 1) & ~1;
            dinv[v] = rsqrtf((float)cval);
        }
        scur[t] = offl;
        for (int i = offl + cval; i < offl + pc; i++) scsrc[i] = N;  // sentinels
    }
    __syncthreads();
    if (v_ok) {
        int slot = atomicAdd(&sbin[key], 1);
        perm[(b << BSH) + slot] = v;  // bucket-local, degree-ascending
    }
    for (int i = t; i < m; i += 1024) {
        unsigned pk = pairs[ebeg + i];
        int slot = atomicAdd(&scur[pk >> 24], 1);
        scsrc[slot] = (int)(pk & 0xFFFFFFu);
    }
    __syncthreads();
    int tot = wsum[0] + wsum[1] + wsum[2] + wsum[3];
    for (int j = t; j < tot; j += 1024) csrc[pbase + j] = scsrc[j];
}

// H[row] = dinv[row] * (X[row] @ W) via mfma_f32_16x16x32_bf16.
// Also writes an all-zero row at index N (sentinel target for csrc pads).
template <bool BF16IN>
__global__ __launch_bounds__(256) void k_gemm(const void* __restrict__ Xv,
                                              const float* __restrict__ W,
                                              const float* __restrict__ dinv,
                                              unsigned* __restrict__ Hout,
                                              int N, int nSlabs, int slabStride) {
    __shared__ float SMEM[4224];
    int t = threadIdx.x;
    int lane = t & 63, w = t >> 6;
    int nn = lane & 15, kq = lane >> 4;

    for (int i = t; i < 1024; i += 256) ((float4*)SMEM)[i] = ((const float4*)W)[i];
    __syncthreads();
    bf16x8 Bf[2][4];
    #pragma unroll
    for (int kt = 0; kt < 2; kt++) {
        #pragma unroll
        for (int ct = 0; ct < 4; ct++) {
            union { bf16x8 v; unsigned short s[8]; } u;
            #pragma unroll
            for (int j = 0; j < 8; j++) {
                int k = kt * 32 + kq * 8 + j;
                u.s[j] = (unsigned short)bf16_rne(SMEM[k * 64 + ct * 16 + nn]);
            }
            Bf[kt][ct] = u.v;
        }
    }
    __syncthreads();

    float* outT = SMEM + w * 1056;

    for (int slab = blockIdx.x * 4 + w; slab < nSlabs; slab += slabStride) {
        int row0 = slab * 16;
        int rowA = min(row0 + nn, N - 1);
        bf16x8 A0, A1;
        if (BF16IN) {
            const uint4* X = (const uint4*)Xv;
            union { uint4 u; bf16x8 v; } a0, a1;
            a0.u = X[(size_t)rowA * 8 + kq];
            a1.u = X[(size_t)rowA * 8 + 4 + kq];
            A0 = a0.v; A1 = a1.v;
        } else {
            const float4* X = (const float4*)Xv;
            float4 f0 = X[(size_t)rowA * 16 + kq * 2];
            float4 f1 = X[(size_t)rowA * 16 + kq * 2 + 1];
            float4 f2 = X[(size_t)rowA * 16 + 8 + kq * 2];
            float4 f3 = X[(size_t)rowA * 16 + 8 + kq * 2 + 1];
            union { bf16x8 v; unsigned short s[8]; } a0, a1;
            a0.s[0] = (unsigned short)bf16_rne(f0.x); a0.s[1] = (unsigned short)bf16_rne(f0.y);
            a0.s[2] = (unsigned short)bf16_rne(f0.z); a0.s[3] = (unsigned short)bf16_rne(f0.w);
            a0.s[4] = (unsigned short)bf16_rne(f1.x); a0.s[5] = (unsigned short)bf16_rne(f1.y);
            a0.s[6] = (unsigned short)bf16_rne(f1.z); a0.s[7] = (unsigned short)bf16_rne(f1.w);
            a1.s[0] = (unsigned short)bf16_rne(f2.x); a1.s[1] = (unsigned short)bf16_rne(f2.y);
            a1.s[2] = (unsigned short)bf16_rne(f2.z); a1.s[3] = (unsigned short)bf16_rne(f2.w);
            a1.s[4] = (unsigned short)bf16_rne(f3.x); a1.s[5] = (unsigned short)bf16_rne(f3.y);
            a1.s[6] = (unsigned short)bf16_rne(f3.z); a1.s[7] = (unsigned short)bf16_rne(f3.w);
            A0 = a0.v; A1 = a1.v;
        }
        float dvm = dinv[rowA];

        f32x4 acc[4];
        #pragma unroll
        for (int ct = 0; ct < 4; ct++) acc[ct] = (f32x4){0.f, 0.f, 0.f, 0.f};
        #pragma unroll
        for (int ct = 0; ct < 4; ct++) {
            acc[ct] = __builtin_amdgcn_mfma_f32_16x16x32_bf16(A0, Bf[0][ct], acc[ct], 0, 0, 0);
            acc[ct] = __builtin_amdgcn_mfma_f32_16x16x32_bf16(A1, Bf[1][ct], acc[ct], 0, 0, 0);
        }

        #pragma unroll
        for (int reg = 0; reg < 4; reg++) {
            int r = kq * 4 + reg;
            float dv = __shfl(dvm, r);
            #pragma unroll
            for (int ct = 0; ct < 4; ct++) {
                outT[r * 66 + ct * 16 + nn] = acc[ct][reg] * dv;
            }
        }
        int rr = lane >> 2;
        int c0 = (lane & 3) * 16;
        int orow = row0 + rr;
        if (orow < N) {
            unsigned pk[8];
            #pragma unroll
            for (int i = 0; i < 8; i++) {
                float lo = outT[rr * 66 + c0 + 2 * i];
                float hi = outT[rr * 66 + c0 + 2 * i + 1];
                pk[i] = bf16_rne(lo) | (bf16_rne(hi) << 16);
            }
            uint4* dst = (uint4*)Hout + (size_t)orow * 8 + (lane & 3) * 2;
            dst[0] = make_uint4(pk[0], pk[1], pk[2], pk[3]);
            dst[1] = make_uint4(pk[4], pk[5], pk[6], pk[7]);
        } else if (orow == N) {
            uint4* dst = (uint4*)Hout + (size_t)N * 8 + (lane & 3) * 2;
            dst[0] = make_uint4(0, 0, 0, 0);
            dst[1] = make_uint4(0, 0, 0, 0);
        }
    }
}

// out[v] = epi( dinv[v] * sum_{j in CSR[v]} H[src_j] + bias ), v = perm[idx].
// One node per 8-lane group; wave's 8 nodes have ~equal degree (sorted).
template <bool RELU_BF16OUT>
__global__ __launch_bounds__(256) void k_agg(const uint4* __restrict__ H,
                                             const int* __restrict__ offsets,
                                             const int* __restrict__ cnt,
                                             const int* __restrict__ csrc,
                                             const float* __restrict__ dinv,
                                             const float* __restrict__ bias,
                                             const int* __restrict__ perm,
                                             void* __restrict__ outv, int N) {
    int t = threadIdx.x;
    int fl = t & 7;
    int idx = blockIdx.x * NPB + (t >> 3);
    if (idx >= N) return;
    int v = perm[idx];
    int beg = offsets[v];
    int deg = cnt[v];
    const int2* cs2 = (const int2*)(csrc + beg);
    const char* hb = (const char*)H + ((unsigned)fl << 4);

    float a0 = 0.f, a1 = 0.f, a2 = 0.f, a3 = 0.f;
    float a4 = 0.f, a5 = 0.f, a6 = 0.f, a7 = 0.f;

#define ACC8(R) do {                                                        \
        uint4 dd = *(const uint4*)(hb + ((unsigned)(R) << 7));              \
        a0 += bf16_lo(dd.x); a1 += bf16_hi(dd.x);                           \
        a2 += bf16_lo(dd.y); a3 += bf16_hi(dd.y);                           \
        a4 += bf16_lo(dd.z); a5 += bf16_hi(dd.z);                           \
        a6 += bf16_lo(dd.w); a7 += bf16_hi(dd.w);                           \
    } while (0)

    int2 ss = cs2[0];
    for (int j = 2; j < deg; j += 2) {
        int2 nx = cs2[j >> 1];
        ACC8(ss.x);
        ACC8(ss.y);
        ss = nx;
    }
    ACC8(ss.x);
    ACC8(ss.y);
#undef ACC8

    float dv = dinv[v];
    const float4* b4 = (const float4*)bias;
    float4 bA = b4[fl * 2];
    float4 bB = b4[fl * 2 + 1];
    float r0 = fmaf(dv, a0, bA.x);
    float r1 = fmaf(dv, a1, bA.y);
    float r2 = fmaf(dv, a2, bA.z);
    float r3 = fmaf(dv, a3, bA.w);
    float r4 = fmaf(dv, a4, bB.x);
    float r5 = fmaf(dv, a5, bB.y);
    float r6 = fmaf(dv, a6, bB.z);
    float r7 = fmaf(dv, a7, bB.w);
    if (RELU_BF16OUT) {
        r0 = fmaxf(r0, 0.f); r1 = fmaxf(r1, 0.f);
        r2 = fmaxf(r2, 0.f); r3 = fmaxf(r3, 0.f);
        r4 = fmaxf(r4, 0.f); r5 = fmaxf(r5, 0.f);
        r6 = fmaxf(r6, 0.f); r7 = fmaxf(r7, 0.f);
        uint4 pk;
        pk.x = bf16_rne(r0) | (bf16_rne(r1) << 16);
        pk.y = bf16_rne(r2) | (bf16_rne(r3) << 16);
        pk.z = bf16_rne(r4) | (bf16_rne(r5) << 16);
        pk.w = bf16_rne(r6) | (bf16_rne(r7) << 16);
        ((uint4*)outv)[(size_t)v * 8 + fl] = pk;
    } else {
        float4* o = (float4*)outv + (size_t)v * 16 + fl * 2;
        o[0] = make_float4(r0, r1, r2, r3);
        o[1] = make_float4(r4, r5, r6, r7);
    }
}

extern "C" void kernel_launch(void* const* d_in, const int* in_sizes, int n_in,
                              void* d_out, int out_size, void* d_ws, size_t ws_size,
                              hipStream_t stream) {
    const float* x  = (const float*)d_in[0];
    const int*   ei = (const int*)d_in[1];  // harness delivers int32
    const float* W1 = (const float*)d_in[2];
    const float* b1 = (const float*)d_in[3];
    const float* W2 = (const float*)d_in[4];
    const float* b2 = (const float*)d_in[5];
    float* out      = (float*)d_out;

    const int N = in_sizes[0] / 64;
    const int E = in_sizes[1] / 2;
    const int* row = ei;
    const int* col = ei + E;
    const int T = E + N;
    const int NB = (N + BSZ - 1) >> BSH;
    const int numTiles = (T + PTILE - 1) / PTILE;

    char* p = (char*)d_ws;
    auto alloc = [&](size_t bytes) { void* r = (void*)p; p += (bytes + 255) & ~(size_t)255; return r; };
    int*      tcnt    = (int*)alloc((size_t)NB * numTiles * 4);
    int*      btot    = (int*)alloc((size_t)(NB + 1) * 4);
    int*      offsets = (int*)alloc((size_t)N * 4);
    int*      cnt     = (int*)alloc((size_t)N * 4);
    float*    dinv    = (float*)alloc((size_t)N * 4);
    int*      perm    = (int*)alloc((size_t)(NB << BSH) * 4);
    unsigned* pairs   = (unsigned*)alloc((size_t)NB * CAP * 4);
    int*      csrc    = (int*)alloc(((size_t)NB * CROW + 64) * 4);
    unsigned* hbuf    = (unsigned*)alloc((size_t)(N + 16) * 32 * 4);
    unsigned* abuf    = (unsigned*)alloc((size_t)(N + 16) * 32 * 4);

    k_count<<<numTiles, 512, 0, stream>>>(col, E, N, NB, numTiles, tcnt);
    k_scan<<<NB, 512, 0, stream>>>(tcnt, btot, NB, numTiles);
    k_scatter<<<numTiles, 512, 0, stream>>>(row, col, E, N, NB, numTiles, tcnt, pairs);
    k_bfill<<<NB, 1024, 0, stream>>>(pairs, btot, N, offsets, cnt, dinv, csrc, perm);

    const int nSlabs = (N + 16) / 16;
    const int GEMM_BLOCKS = 1024;
    const int SLAB_STRIDE = GEMM_BLOCKS * 4;
    const int GB = (N + NPB - 1) / NPB;

    k_gemm<false><<<GEMM_BLOCKS, 256, 0, stream>>>(x, W1, dinv, hbuf, N, nSlabs, SLAB_STRIDE);
    k_agg<true><<<GB, 256, 0, stream>>>((const uint4*)hbuf, offsets, cnt, csrc, dinv, b1, perm, abuf, N);
    k_gemm<true><<<GEMM_BLOCKS, 256, 0, stream>>>(abuf, W2, dinv, hbuf, N, nSlabs, SLAB_STRIDE);
    k_agg<false><<<GB, 256, 0, stream>>>((const uint4*)hbuf, offsets, cnt, csrc, dinv, b2, perm, out, N);
}

// Round 9
// 200.228 us; speedup vs baseline: 2.4801x; 1.0911x over previous
//
#include <hip/hip_runtime.h>

// ---------------------------------------------------------------------------
// GCN 2-layer forward, round 21.
// Round-20 post-mortem: REGRESSED 198->218.5. Perm'd agg doubled WRITE_SIZE
// (12.5->25MB, partial-line RFO on scattered 128B rows) and +8MB FETCH.
// Coalescing > divergence (3rd confirmation). Perm reverted; base = r17.
// Round-21 delta (ONE mechanism): move src-side dinv into agg's gather.
//   * gemm computes UNSCALED H = bf16(xW). The 8 adds per uint4 in agg
//     become fmaf(dinv[src], val, acc) - same instr count; dinv[src] is a
//     4B L2-resident load (400KB table). dinv[N]=0 handles sentinel pads.
//   * gemm1 now depends only on x,W1 -> fused into k_count launch via
//     block-range split (416 count blocks || 1024 gemm blocks, disjoint
//     data, no sync; r19's trick minus deg-atomics minus capped tail).
// Pipeline: [count||gemm1], scan, scatter, bfill, agg1, gemm2, agg2 = 7.
// ---------------------------------------------------------------------------

#define NPB 32       // nodes per block (agg): 256 thr / 8-lane groups
#define BSH 8        // bucket shift: 256 nodes per bucket
#define BSZ 256
#define PTILE 4096   // messages per partition tile
#define CAP 6144     // fixed bucket capacity (slots)
#define PADALLOW 3856
#define CROW (CAP + PADALLOW)  // per-bucket csrc region
#define GEMMB 1024   // gemm1 blocks inside k_cntgm

typedef __attribute__((ext_vector_type(8))) short bf16x8;
typedef __attribute__((ext_vector_type(4))) float f32x4;

__device__ __forceinline__ unsigned bf16_rne(float f) {
    unsigned b = __float_as_uint(f);
    return (b + 0x7fffu + ((b >> 16) & 1u)) >> 16;
}
__device__ __forceinline__ float bf16_lo(unsigned u) { return __uint_as_float(u << 16); }
__device__ __forceinline__ float bf16_hi(unsigned u) { return __uint_as_float(u & 0xffff0000u); }

// H[row] = (X[row] @ W) UNSCALED, bf16 out; zero sentinel row at N.
// NT = block threads. blkLocal/nBlkLocal define slab striding.
template <bool BF16IN, int NT>
__device__ __forceinline__ void gemm_body(const void* __restrict__ Xv,
                                          const float* __restrict__ W,
                                          unsigned* __restrict__ Hout,
                                          int N, int nSlabs, int blkLocal,
                                          int nBlkLocal, float* SMEM) {
    int t = threadIdx.x;
    int lane = t & 63, w = t >> 6;
    int nn = lane & 15, kq = lane >> 4;
    constexpr int NW = NT / 64;

    for (int i = t; i < 1024; i += NT) ((float4*)SMEM)[i] = ((const float4*)W)[i];
    __syncthreads();
    bf16x8 Bf[2][4];
    #pragma unroll
    for (int kt = 0; kt < 2; kt++) {
        #pragma unroll
        for (int ct = 0; ct < 4; ct++) {
            union { bf16x8 v; unsigned short s[8]; } u;
            #pragma unroll
            for (int j = 0; j < 8; j++) {
                int k = kt * 32 + kq * 8 + j;
                u.s[j] = (unsigned short)bf16_rne(SMEM[k * 64 + ct * 16 + nn]);
            }
            Bf[kt][ct] = u.v;
        }
    }
    __syncthreads();  // W region dead; SMEM becomes per-wave transpose scratch

    float* outT = SMEM + w * 1056;  // 16 rows x 66 floats

    for (int slab = blkLocal * NW + w; slab < nSlabs; slab += nBlkLocal * NW) {
        int row0 = slab * 16;
        int rowA = min(row0 + nn, N - 1);
        bf16x8 A0, A1;
        if (BF16IN) {
            const uint4* X = (const uint4*)Xv;  // row = 8 uint4
            union { uint4 u; bf16x8 v; } a0, a1;
            a0.u = X[(size_t)rowA * 8 + kq];
            a1.u = X[(size_t)rowA * 8 + 4 + kq];
            A0 = a0.v; A1 = a1.v;
        } else {
            const float4* X = (const float4*)Xv;  // row = 16 float4
            float4 f0 = X[(size_t)rowA * 16 + kq * 2];
            float4 f1 = X[(size_t)rowA * 16 + kq * 2 + 1];
            float4 f2 = X[(size_t)rowA * 16 + 8 + kq * 2];
            float4 f3 = X[(size_t)rowA * 16 + 8 + kq * 2 + 1];
            union { bf16x8 v; unsigned short s[8]; } a0, a1;
            a0.s[0] = (unsigned short)bf16_rne(f0.x); a0.s[1] = (unsigned short)bf16_rne(f0.y);
            a0.s[2] = (unsigned short)bf16_rne(f0.z); a0.s[3] = (unsigned short)bf16_rne(f0.w);
            a0.s[4] = (unsigned short)bf16_rne(f1.x); a0.s[5] = (unsigned short)bf16_rne(f1.y);
            a0.s[6] = (unsigned short)bf16_rne(f1.z); a0.s[7] = (unsigned short)bf16_rne(f1.w);
            a1.s[0] = (unsigned short)bf16_rne(f2.x); a1.s[1] = (unsigned short)bf16_rne(f2.y);
            a1.s[2] = (unsigned short)bf16_rne(f2.z); a1.s[3] = (unsigned short)bf16_rne(f2.w);
            a1.s[4] = (unsigned short)bf16_rne(f3.x); a1.s[5] = (unsigned short)bf16_rne(f3.y);
            a1.s[6] = (unsigned short)bf16_rne(f3.z); a1.s[7] = (unsigned short)bf16_rne(f3.w);
            A0 = a0.v; A1 = a1.v;
        }

        f32x4 acc[4];
        #pragma unroll
        for (int ct = 0; ct < 4; ct++) acc[ct] = (f32x4){0.f, 0.f, 0.f, 0.f};
        #pragma unroll
        for (int ct = 0; ct < 4; ct++) {
            acc[ct] = __builtin_amdgcn_mfma_f32_16x16x32_bf16(A0, Bf[0][ct], acc[ct], 0, 0, 0);
            acc[ct] = __builtin_amdgcn_mfma_f32_16x16x32_bf16(A1, Bf[1][ct], acc[ct], 0, 0, 0);
        }

        #pragma unroll
        for (int reg = 0; reg < 4; reg++) {
            int r = kq * 4 + reg;
            #pragma unroll
            for (int ct = 0; ct < 4; ct++) {
                outT[r * 66 + ct * 16 + nn] = acc[ct][reg];
            }
        }
        int rr = lane >> 2;
        int c0 = (lane & 3) * 16;
        int orow = row0 + rr;
        if (orow < N) {
            unsigned pk[8];
            #pragma unroll
            for (int i = 0; i < 8; i++) {
                float lo = outT[rr * 66 + c0 + 2 * i];
                float hi = outT[rr * 66 + c0 + 2 * i + 1];
                pk[i] = bf16_rne(lo) | (bf16_rne(hi) << 16);
            }
            uint4* dst = (uint4*)Hout + (size_t)orow * 8 + (lane & 3) * 2;
            dst[0] = make_uint4(pk[0], pk[1], pk[2], pk[3]);
            dst[1] = make_uint4(pk[4], pk[5], pk[6], pk[7]);
        } else if (orow == N) {  // zero sentinel row
            uint4* dst = (uint4*)Hout + (size_t)N * 8 + (lane & 3) * 2;
            dst[0] = make_uint4(0, 0, 0, 0);
            dst[1] = make_uint4(0, 0, 0, 0);
        }
    }
}

// Fused: per-tile bucket histogram (blocks < numTiles) || gemm1 (next GEMMB).
__global__ __launch_bounds__(512) void k_cntgm(const int* __restrict__ coli,
                                               int E, int N, int NB, int numTiles,
                                               int* __restrict__ tcnt,
                                               const float* __restrict__ x,
                                               const float* __restrict__ W1,
                                               unsigned* __restrict__ hbuf,
                                               int nSlabs) {
    __shared__ float SMEM[8448];  // gemm: W + 8-wave scratch; count: hist
    int bid = blockIdx.x;
    if (bid >= numTiles) {
        gemm_body<false, 512>(x, W1, hbuf, N, nSlabs, bid - numTiles, GEMMB, SMEM);
        return;
    }
    int* hist = (int*)SMEM;
    int t = threadIdx.x;
    int T = E + N;
    int tstart = bid * PTILE;
    int m = min(PTILE, T - tstart);
    for (int b = t; b < NB; b += 512) hist[b] = 0;
    __syncthreads();
    for (int i = t; i < m; i += 512) {
        int g = tstart + i;
        int c = (g < E) ? coli[g] : (g - E);
        atomicAdd(&hist[c >> BSH], 1);
    }
    __syncthreads();
    for (int b = t; b < NB; b += 512) tcnt[(size_t)bid * NB + b] = hist[b];
}

// Block-per-bucket exclusive scan over tiles (chunked, wave-shuffle).
__global__ __launch_bounds__(512) void k_scan(int* __restrict__ tcnt,
                                              int* __restrict__ btot,
                                              int NB, int numTiles) {
    __shared__ int wsum[8];
    int b = blockIdx.x;
    int t = threadIdx.x;
    int lane = t & 63, wid = t >> 6;
    int base = 0;
    for (int c0 = 0; c0 < numTiles; c0 += 512) {
        int tt = c0 + t;
        int v = (tt < numTiles) ? tcnt[(size_t)tt * NB + b] : 0;
        int inc = v;
        #pragma unroll
        for (int d = 1; d < 64; d <<= 1) {
            int o = __shfl_up(inc, d);
            if (lane >= d) inc += o;
        }
        if (lane == 63) wsum[wid] = inc;
        __syncthreads();
        int woff = 0, ctot = 0;
        #pragma unroll
        for (int i = 0; i < 8; i++) {
            int s = wsum[i];
            if (i < wid) woff += s;
            ctot += s;
        }
        if (tt < numTiles) tcnt[(size_t)tt * NB + b] = b * CAP + base + woff + inc - v;
        base += ctot;
        __syncthreads();
    }
    if (t == 0) btot[b] = base;
}

// Scatter: LDS counting sort per tile, coalesced pairs writes.
__global__ __launch_bounds__(512) void k_scatter(const int* __restrict__ rowi,
                                                 const int* __restrict__ coli,
                                                 int E, int N, int NB, int numTiles,
                                                 const int* __restrict__ tcnt,
                                                 unsigned* __restrict__ pairs) {
    __shared__ int hist[512];
    __shared__ int lbase[512];
    __shared__ int gbase[512];
    __shared__ unsigned sorted[PTILE];
    __shared__ unsigned short sbkt[PTILE];
    __shared__ int wsum[8];
    int t = threadIdx.x;
    int T = E + N;
    int tile = blockIdx.x;
    int tstart = tile * PTILE;
    int m = min(PTILE, T - tstart);
    int lane = t & 63, wid = t >> 6;
    for (int b = t; b < NB; b += 512) {
        hist[b] = 0;
        gbase[b] = tcnt[(size_t)tile * NB + b];
    }
    __syncthreads();
    int c_reg[8];
    #pragma unroll
    for (int k = 0; k < 8; k++) {
        int i = t + k * 512;
        int c = 0;
        if (i < m) {
            int g = tstart + i;
            c = (g < E) ? coli[g] : (g - E);
            atomicAdd(&hist[c >> BSH], 1);
        }
        c_reg[k] = c;
    }
    __syncthreads();
    {   // block exclusive scan of hist -> lbase
        int v = (t < NB) ? hist[t] : 0;
        int inc = v;
        #pragma unroll
        for (int d = 1; d < 64; d <<= 1) {
            int o = __shfl_up(inc, d);
            if (lane >= d) inc += o;
        }
        if (lane == 63) wsum[wid] = inc;
        __syncthreads();
        int woff = 0;
        for (int i = 0; i < wid; i++) woff += wsum[i];
        if (t < NB) lbase[t] = woff + inc - v;
        __syncthreads();
    }
    for (int b = t; b < NB; b += 512) hist[b] = 0;  // reuse as cursors
    __syncthreads();
    #pragma unroll
    for (int k = 0; k < 8; k++) {
        int i = t + k * 512;
        if (i < m) {
            int g = tstart + i;
            int c = c_reg[k];
            int r = (g < E) ? rowi[g] : c;  // self-loop tail has r == c
            int b = c >> BSH;
            int lr = atomicAdd(&hist[b], 1);
            int pos = lbase[b] + lr;
            sorted[pos] = (unsigned)r | ((unsigned)(c & (BSZ - 1)) << 24);
            sbkt[pos] = (unsigned short)b;
        }
    }
    __syncthreads();
    for (int j = t; j < m; j += 512) {
        int b = sbkt[j];
        pairs[gbase[b] + (j - lbase[b])] = sorted[j];
    }
}

// One block per bucket: per-node histogram, padded scan, build csrc in LDS,
// coalesced copy out. Also writes dinv (incl. dinv[N] = 0 sentinel).
__global__ __launch_bounds__(1024) void k_bfill(const unsigned* __restrict__ pairs,
                                                const int* __restrict__ btot,
                                                int N,
                                                int* __restrict__ offsets,
                                                int* __restrict__ cnt,
                                                float* __restrict__ dinv,
                                                int* __restrict__ csrc) {
    __shared__ int scnt[BSZ];
    __shared__ int scur[BSZ];
    __shared__ int wsum[4];
    __shared__ int scsrc[CROW];
    int b = blockIdx.x;
    int t = threadIdx.x;
    int ebeg = b * CAP;
    int m = btot[b];
    int pbase = b * CROW;
    int lane = t & 63, wid = t >> 6;
    if (b == 0 && t == 0) dinv[N] = 0.0f;  // sentinel row scale
    if (t < BSZ) scnt[t] = 0;
    __syncthreads();
    for (int i = t; i < m; i += 1024) atomicAdd(&scnt[pairs[ebeg + i] >> 24], 1);
    __syncthreads();
    int cval = 0, pc = 0, inc = 0;
    if (t < BSZ) {
        cval = scnt[t];
        pc = (cval + 15) & ~15;
        inc = pc;
        #pragma unroll
        for (int d = 1; d < 64; d <<= 1) {
            int o = __shfl_up(inc, d);
            if (lane >= d) inc += o;
        }
        if (lane == 63) wsum[wid] = inc;
    }
    __syncthreads();
    if (t < BSZ) {
        int woff = 0;
        for (int i = 0; i < wid; i++) woff += wsum[i];
        int offl = woff + inc - pc;
        int v = (b << BSH) + t;
        if (v < N) {
            offsets[v] = pbase + offl;
            cnt[v] = (cval + 1) & ~1;
            dinv[v] = rsqrtf((float)cval);
        }
        scur[t] = offl;
        for (int i = offl + cval; i < offl + pc; i++) scsrc[i] = N;  // sentinels
    }
    __syncthreads();
    for (int i = t; i < m; i += 1024) {
        unsigned pk = pairs[ebeg + i];
        int slot = atomicAdd(&scur[pk >> 24], 1);
        scsrc[slot] = (int)(pk & 0xFFFFFFu);
    }
    __syncthreads();
    int tot = wsum[0] + wsum[1] + wsum[2] + wsum[3];
    for (int j = t; j < tot; j += 1024) csrc[pbase + j] = scsrc[j];
}

// Solo gemm kernel (layer 2): H = (abuf @ W2) unscaled.
template <bool BF16IN>
__global__ __launch_bounds__(256) void k_gemm(const void* __restrict__ Xv,
                                              const float* __restrict__ W,
                                              unsigned* __restrict__ Hout,
                                              int N, int nSlabs, int nBlk) {
    __shared__ float SMEM[4224];
    gemm_body<BF16IN, 256>(Xv, W, Hout, N, nSlabs, blockIdx.x, nBlk, SMEM);
}

// out[v] = epi( dinv[v] * sum_{j} dinv[src_j]*H[src_j] + bias )
// One node per 8-lane group; lane-private accumulators; fmaf applies
// dinv[src] (same instr count as add; dinv table is L2-resident).
template <bool RELU_BF16OUT>
__global__ __launch_bounds__(256) void k_agg(const uint4* __restrict__ H,
                                             const int* __restrict__ offsets,
                                             const int* __restrict__ cnt,
                                             const int* __restrict__ csrc,
                                             const float* __restrict__ dinv,
                                             const float* __restrict__ bias,
                                             void* __restrict__ outv, int N) {
    int t = threadIdx.x;
    int fl = t & 7;
    int v = blockIdx.x * NPB + (t >> 3);
    if (v >= N) return;
    int beg = offsets[v];
    int deg = cnt[v];
    const int2* cs2 = (const int2*)(csrc + beg);
    const char* hb = (const char*)H + ((unsigned)fl << 4);

    float a0 = 0.f, a1 = 0.f, a2 = 0.f, a3 = 0.f;
    float a4 = 0.f, a5 = 0.f, a6 = 0.f, a7 = 0.f;

#define ACC8(R, D) do {                                                     \
        uint4 dd = *(const uint4*)(hb + ((unsigned)(R) << 7));              \
        a0 = fmaf(D, bf16_lo(dd.x), a0); a1 = fmaf(D, bf16_hi(dd.x), a1);   \
        a2 = fmaf(D, bf16_lo(dd.y), a2); a3 = fmaf(D, bf16_hi(dd.y), a3);   \
        a4 = fmaf(D, bf16_lo(dd.z), a4); a5 = fmaf(D, bf16_hi(dd.z), a5);   \
        a6 = fmaf(D, bf16_lo(dd.w), a6); a7 = fmaf(D, bf16_hi(dd.w), a7);   \
    } while (0)

    int2 ss = cs2[0];
    float dsx = dinv[ss.x], dsy = dinv[ss.y];
    for (int j = 2; j < deg; j += 2) {
        int2 nx = cs2[j >> 1];             // prefetched 1-deep
        float dnx = dinv[nx.x], dny = dinv[nx.y];
        ACC8(ss.x, dsx);
        ACC8(ss.y, dsy);
        ss = nx; dsx = dnx; dsy = dny;
    }
    ACC8(ss.x, dsx);
    ACC8(ss.y, dsy);
#undef ACC8

    float dv = dinv[v];
    const float4* b4 = (const float4*)bias;
    float4 bA = b4[fl * 2];
    float4 bB = b4[fl * 2 + 1];
    float r0 = fmaf(dv, a0, bA.x);
    float r1 = fmaf(dv, a1, bA.y);
    float r2 = fmaf(dv, a2, bA.z);
    float r3 = fmaf(dv, a3, bA.w);
    float r4 = fmaf(dv, a4, bB.x);
    float r5 = fmaf(dv, a5, bB.y);
    float r6 = fmaf(dv, a6, bB.z);
    float r7 = fmaf(dv, a7, bB.w);
    if (RELU_BF16OUT) {
        r0 = fmaxf(r0, 0.f); r1 = fmaxf(r1, 0.f);
        r2 = fmaxf(r2, 0.f); r3 = fmaxf(r3, 0.f);
        r4 = fmaxf(r4, 0.f); r5 = fmaxf(r5, 0.f);
        r6 = fmaxf(r6, 0.f); r7 = fmaxf(r7, 0.f);
        uint4 pk;
        pk.x = bf16_rne(r0) | (bf16_rne(r1) << 16);
        pk.y = bf16_rne(r2) | (bf16_rne(r3) << 16);
        pk.z = bf16_rne(r4) | (bf16_rne(r5) << 16);
        pk.w = bf16_rne(r6) | (bf16_rne(r7) << 16);
        ((uint4*)outv)[(size_t)v * 8 + fl] = pk;
    } else {
        float4* o = (float4*)outv + (size_t)v * 16 + fl * 2;
        o[0] = make_float4(r0, r1, r2, r3);
        o[1] = make_float4(r4, r5, r6, r7);
    }
}

extern "C" void kernel_launch(void* const* d_in, const int* in_sizes, int n_in,
                              void* d_out, int out_size, void* d_ws, size_t ws_size,
                              hipStream_t stream) {
    const float* x  = (const float*)d_in[0];
    const int*   ei = (const int*)d_in[1];  // harness delivers int32
    const float* W1 = (const float*)d_in[2];
    const float* b1 = (const float*)d_in[3];
    const float* W2 = (const float*)d_in[4];
    const float* b2 = (const float*)d_in[5];
    float* out      = (float*)d_out;

    const int N = in_sizes[0] / 64;
    const int E = in_sizes[1] / 2;
    const int* row = ei;
    const int* col = ei + E;
    const int T = E + N;
    const int NB = (N + BSZ - 1) >> BSH;
    const int numTiles = (T + PTILE - 1) / PTILE;

    char* p = (char*)d_ws;
    auto alloc = [&](size_t bytes) { void* r = (void*)p; p += (bytes + 255) & ~(size_t)255; return r; };
    int*      tcnt    = (int*)alloc((size_t)NB * numTiles * 4);
    int*      btot    = (int*)alloc((size_t)(NB + 1) * 4);
    int*      offsets = (int*)alloc((size_t)N * 4);
    int*      cnt     = (int*)alloc((size_t)N * 4);
    float*    dinv    = (float*)alloc((size_t)(N + 16) * 4);  // +sentinel N
    unsigned* pairs   = (unsigned*)alloc((size_t)NB * CAP * 4);
    int*      csrc    = (int*)alloc(((size_t)NB * CROW + 64) * 4);
    unsigned* hbuf    = (unsigned*)alloc((size_t)(N + 16) * 32 * 4);  // bf16, +zero row
    unsigned* abuf    = (unsigned*)alloc((size_t)(N + 16) * 32 * 4);  // bf16, +zero row

    const int nSlabs = (N + 16) / 16;  // covers zero sentinel row N
    const int GB = (N + NPB - 1) / NPB;

    k_cntgm<<<numTiles + GEMMB, 512, 0, stream>>>(col, E, N, NB, numTiles, tcnt,
                                                  x, W1, hbuf, nSlabs);
    k_scan<<<NB, 512, 0, stream>>>(tcnt, btot, NB, numTiles);
    k_scatter<<<numTiles, 512, 0, stream>>>(row, col, E, N, NB, numTiles, tcnt, pairs);
    k_bfill<<<NB, 1024, 0, stream>>>(pairs, btot, N, offsets, cnt, dinv, csrc);

    k_agg<true><<<GB, 256, 0, stream>>>((const uint4*)hbuf, offsets, cnt, csrc, dinv, b1, abuf, N);
    k_gemm<true><<<1024, 256, 0, stream>>>(abuf, W2, hbuf, N, nSlabs, 1024);
    k_agg<false><<<GB, 256, 0, stream>>>((const uint4*)hbuf, offsets, cnt, csrc, dinv, b2, out, N);
}